// Round 1
// baseline (3171.988 us; speedup 1.0000x reference)
//
#include <hip/hip_runtime.h>
#include <math.h>

// Problem constants (B,N,M,K from reference setup_inputs)
constexpr int Bq = 2;
constexpr int Nq = 100000;
constexpr int Mq = 25000;
constexpr int Kq = 16;
// rows of (B,M,K) = 800000 = 3125*256 exactly
// B*N = 200000 ; B*M = 50000 = 3125*16 exactly

// ---- workspace layout (bytes) ----
constexpr size_t OFF_VI = 0;              // 800000*12*4  = 38,400,000
constexpr size_t OFF_Y8 = 38400000;       // 50000*128*4  = 25,600,000
constexpr size_t OFF_Y9 = 64000000;       // 25,600,000
constexpr size_t OFF_DS = 89600000;       // 784 doubles (8-aligned)
constexpr size_t OFF_FS = OFF_DS + 8192;  // 784 floats
// total ~89.7 MB

// ---- stat-group offsets, shared index space for double sums and float stats.
// [off..off+C) = sum (later mean), [off+C..off+2C) = sumsq (later invstd)
constexpr int G_BN1 = 0;    // C=32  n=800000  mlp_conv pre-act
constexpr int G_BN5 = 64;   // C=8   n=800000  wn0 pre-act
constexpr int G_BN4 = 80;   // C=32  n=200000  u1 pre-act
constexpr int G_BN2 = 144;  // C=32  n=800000  gu pre-act
constexpr int G_BN6 = 208;  // C=8   n=800000  wn1 pre-act
constexpr int G_BN3 = 224;  // C=8   n=800000  gm0 pre-act
constexpr int G_BN7 = 240;  // C=16  n=800000  wn2 pre-act
constexpr int G_BN8 = 272;  // C=128 n=50000   u2 pre-act
constexpr int G_BN9 = 528;  // C=128 n=50000   us pre-act

struct P {
  const float *dxyz,*sxyz,*dfeat,*dnorm,*snorm;
  const float *w_mlp,*b_mlp,*w_gu,*b_gu,*w_gm0,*b_gm0,*w_gm1,*b_gm1;
  const float *w_u1,*b_u1,*w_wn0,*b_wn0,*w_wn1,*b_wn1,*w_wn2,*b_wn2;
  const float *w_u2,*b_u2,*w_us,*b_us;
  const int* nei;
  float* vi; float* y8; float* y9; double* ds; float* fs; float* out;
};

__device__ __forceinline__ float lrelu(float x){ return x > 0.f ? x : 0.1f*x; }

// ---------------------------------------------------------------- P1: vi + bn1/bn5 moments
__global__ __launch_bounds__(256) void k_vi(P p){
  __shared__ float ls[80]; // [0..31] y1 sum [32..63] y1 sq [64..71] y5 sum [72..79] y5 sq
  int t = threadIdx.x;
  if (t < 80) ls[t] = 0.f;
  __syncthreads();

  int row = blockIdx.x*256 + t;                 // 800000 rows exactly
  int b   = row / (Mq*Kq);
  int rem = row - b*(Mq*Kq);
  int m   = rem >> 4;
  int bm  = b*Mq + m;
  int idx = p.nei[row];

  const float* gx = p.dxyz  + ((size_t)b*Nq + idx)*3;
  const float* gn = p.dnorm + ((size_t)b*Nq + idx)*3;
  const float* sx = p.sxyz  + (size_t)bm*3;
  const float* sn = p.snorm + (size_t)bm*3;

  float lx = gx[0]-sx[0], ly = gx[1]-sx[1], lz = gx[2]-sx[2];
  float gnx = gn[0], gny = gn[1], gnz = gn[2];
  float snx = sn[0], sny = sn[1], snz = sn[2];

  float rn = sqrtf(lx*lx + ly*ly + lz*lz);
  float rd = fmaxf(rn, 1e-12f);
  float rx = lx/rd, ry = ly/rd, rz = lz/rd;
  float proj = snx*rx + sny*ry + snz*rz;
  float vx = snx - proj*rx, vy = sny - proj*ry, vz = snz - proj*rz;
  float vn = sqrtf(vx*vx + vy*vy + vz*vz);
  float vd = fmaxf(vn, 1e-12f);
  vx /= vd; vy /= vd; vz /= vd;
  float wx = ry*vz - rz*vy, wy = rz*vx - rx*vz, wz = rx*vy - ry*vx;
  float wn = sqrtf(wx*wx + wy*wy + wz*wz);
  float wd = fmaxf(wn, 1e-12f);
  wx /= wd; wy /= wd; wz /= wd;
  float cx = gny*snz - gnz*sny, cy = gnz*snx - gnx*snz, cz = gnx*sny - gny*snx;

  float v[12];
  v[0] = gnx*snx + gny*sny + gnz*snz;     // t1
  v[1] = proj;                            // t2
  v[2] = rx*gnx + ry*gny + rz*gnz;        // t3
  v[3] = lx*snx + ly*sny + lz*snz;        // t4
  v[4] = v[2];                            // t5 == t3
  v[5] = gnx*vx + gny*vy + gnz*vz;        // t6
  v[6] = gnx*wx + gny*wy + gnz*wz;        // t7
  v[7] = lx*cx + ly*cy + lz*cz;           // t8
  v[8] = rn;                              // t9
  v[9] = lx; v[10] = ly; v[11] = lz;

  float4* vo = (float4*)(p.vi + (size_t)row*12);
  vo[0] = make_float4(v[0],v[1],v[2],v[3]);
  vo[1] = make_float4(v[4],v[5],v[6],v[7]);
  vo[2] = make_float4(v[8],v[9],v[10],v[11]);

  int lane = t & 63;
  // y1 = mlp_conv pre-act, skewed channel order to avoid same-address LDS atomics
  #pragma unroll
  for (int i = 0; i < 32; i++){
    int c = (lane + i) & 31;
    float y = p.b_mlp[c];
    #pragma unroll
    for (int j = 0; j < 12; j++) y += p.w_mlp[c*12 + j]*v[j];
    atomicAdd(&ls[c], y); atomicAdd(&ls[32+c], y*y);
  }
  // y5 = wn0 pre-act
  #pragma unroll
  for (int i = 0; i < 8; i++){
    int c = (lane + i) & 7;
    float y = p.b_wn0[c];
    #pragma unroll
    for (int j = 0; j < 12; j++) y += p.w_wn0[c*12 + j]*v[j];
    atomicAdd(&ls[64+c], y); atomicAdd(&ls[72+c], y*y);
  }
  __syncthreads();
  if (t < 32){
    atomicAdd(&p.ds[G_BN1+t], (double)ls[t]);
    atomicAdd(&p.ds[G_BN1+32+t], (double)ls[32+t]);
  } else if (t < 40){
    int c = t - 32;
    atomicAdd(&p.ds[G_BN5+c], (double)ls[64+c]);
    atomicAdd(&p.ds[G_BN5+8+c], (double)ls[72+c]);
  }
}

// ---------------------------------------------------------------- P1b: bn4 (u1) moments over B*N
__global__ __launch_bounds__(256) void k_u1s(P p){
  __shared__ float ls[64];
  int t = threadIdx.x;
  if (t < 64) ls[t] = 0.f;
  __syncthreads();
  int row = blockIdx.x*256 + t;
  if (row < Bq*Nq){
    const float4* f4 = (const float4*)(p.dfeat + (size_t)row*64);
    float fr[64];
    #pragma unroll
    for (int q = 0; q < 16; q++){
      float4 x = f4[q];
      fr[q*4+0]=x.x; fr[q*4+1]=x.y; fr[q*4+2]=x.z; fr[q*4+3]=x.w;
    }
    int lane = t & 63;
    #pragma unroll
    for (int i = 0; i < 32; i++){
      int c = (lane + i) & 31;
      float y = p.b_u1[c];
      #pragma unroll
      for (int j = 0; j < 64; j++) y += p.w_u1[c*64 + j]*fr[j];
      atomicAdd(&ls[c], y); atomicAdd(&ls[32+c], y*y);
    }
  }
  __syncthreads();
  if (t < 32){
    atomicAdd(&p.ds[G_BN4+t], (double)ls[t]);
    atomicAdd(&p.ds[G_BN4+32+t], (double)ls[32+t]);
  }
}

// ---------------------------------------------------------------- stat finalize
__device__ __forceinline__ void fin_group(const double* ds, float* fs, int off, int C, double n){
  for (int c = threadIdx.x; c < C; c += blockDim.x){
    double s = ds[off+c], q = ds[off+C+c];
    double mu = s/n;
    double va = q/n - mu*mu;
    if (va < 0.0) va = 0.0;
    fs[off+c]   = (float)mu;
    fs[off+C+c] = 1.f/sqrtf((float)va + 1e-5f);
  }
}
__global__ void k_fin1(P p){ fin_group(p.ds,p.fs,G_BN1,32,800000.0); fin_group(p.ds,p.fs,G_BN5,8,800000.0); fin_group(p.ds,p.fs,G_BN4,32,200000.0); }
__global__ void k_fin2(P p){ fin_group(p.ds,p.fs,G_BN2,32,800000.0); fin_group(p.ds,p.fs,G_BN6,8,800000.0); }
__global__ void k_fin3(P p){ fin_group(p.ds,p.fs,G_BN3,8,800000.0);  fin_group(p.ds,p.fs,G_BN7,16,800000.0); }
__global__ void k_fin4(P p){ fin_group(p.ds,p.fs,G_BN8,128,50000.0); fin_group(p.ds,p.fs,G_BN9,128,50000.0); }

// helpers to recompute the small chains from vi
__device__ __forceinline__ void load_vi(const P& p, int row, float v[12]){
  const float4* vp = (const float4*)(p.vi + (size_t)row*12);
  float4 a = vp[0], b = vp[1], c = vp[2];
  v[0]=a.x; v[1]=a.y; v[2]=a.z; v[3]=a.w;
  v[4]=b.x; v[5]=b.y; v[6]=b.z; v[7]=b.w;
  v[8]=c.x; v[9]=c.y; v[10]=c.z; v[11]=c.w;
}
__device__ __forceinline__ void featpe(const P& p, const float v[12], float fp[32]){
  #pragma unroll
  for (int c = 0; c < 32; c++){
    float y = p.b_mlp[c];
    #pragma unroll
    for (int j = 0; j < 12; j++) y += p.w_mlp[c*12+j]*v[j];
    fp[c] = fmaxf((y - p.fs[G_BN1+c])*p.fs[G_BN1+32+c], 0.f);
  }
}
__device__ __forceinline__ void wchain0(const P& p, const float v[12], float w0[8]){
  #pragma unroll
  for (int c = 0; c < 8; c++){
    float y = p.b_wn0[c];
    #pragma unroll
    for (int j = 0; j < 12; j++) y += p.w_wn0[c*12+j]*v[j];
    w0[c] = fmaxf((y - p.fs[G_BN5+c])*p.fs[G_BN5+8+c], 0.f);
  }
}

// ---------------------------------------------------------------- P2: bn2/bn6 moments
__global__ __launch_bounds__(256) void k_s2(P p){
  __shared__ float ls[80]; // bn2 sum/sq [0..63], bn6 sum/sq [64..79]
  int t = threadIdx.x;
  if (t < 80) ls[t] = 0.f;
  __syncthreads();
  int row = blockIdx.x*256 + t;
  float v[12]; load_vi(p, row, v);
  float fp[32]; featpe(p, v, fp);
  int lane = t & 63;
  #pragma unroll
  for (int i = 0; i < 32; i++){
    int c = (lane + i) & 31;
    float y = p.b_gu[c];
    #pragma unroll
    for (int j = 0; j < 32; j++) y += p.w_gu[c*32+j]*fp[j];
    atomicAdd(&ls[c], y); atomicAdd(&ls[32+c], y*y);
  }
  float w0[8]; wchain0(p, v, w0);
  #pragma unroll
  for (int i = 0; i < 8; i++){
    int c = (lane + i) & 7;
    float y = p.b_wn1[c];
    #pragma unroll
    for (int j = 0; j < 8; j++) y += p.w_wn1[c*8+j]*w0[j];
    atomicAdd(&ls[64+c], y); atomicAdd(&ls[72+c], y*y);
  }
  __syncthreads();
  if (t < 32){
    atomicAdd(&p.ds[G_BN2+t], (double)ls[t]);
    atomicAdd(&p.ds[G_BN2+32+t], (double)ls[32+t]);
  } else if (t < 40){
    int c = t - 32;
    atomicAdd(&p.ds[G_BN6+c], (double)ls[64+c]);
    atomicAdd(&p.ds[G_BN6+8+c], (double)ls[72+c]);
  }
}

// ---------------------------------------------------------------- P3: bn3/bn7 moments (needs max over K)
__global__ __launch_bounds__(256) void k_s3(P p){
  __shared__ float ls[48]; // bn3 sum [0..7] sq [8..15]; bn7 sum [16..31] sq [32..47]
  int t = threadIdx.x;
  if (t < 48) ls[t] = 0.f;
  __syncthreads();
  int lane = t & 63;
  int k  = lane & 15;
  int pl = (t >> 6)*4 + (lane >> 4);
  int pg = blockIdx.x*16 + pl;        // 50000 points exactly (3125 blocks)
  int row = pg*16 + k;

  float v[12]; load_vi(p, row, v);
  float fp[32]; featpe(p, v, fp);
  float g[32];
  #pragma unroll
  for (int c = 0; c < 32; c++){
    float y = p.b_gu[c];
    #pragma unroll
    for (int j = 0; j < 32; j++) y += p.w_gu[c*32+j]*fp[j];
    g[c] = (y - p.fs[G_BN2+c])*p.fs[G_BN2+32+c];   // guidance (no relu)
  }
  #pragma unroll
  for (int c = 0; c < 32; c++){
    float mx = g[c];
    mx = fmaxf(mx, __shfl_xor(mx, 1, 16));
    mx = fmaxf(mx, __shfl_xor(mx, 2, 16));
    mx = fmaxf(mx, __shfl_xor(mx, 4, 16));
    mx = fmaxf(mx, __shfl_xor(mx, 8, 16));
    g[c] -= mx;                                    // guidance - g_key
  }
  #pragma unroll
  for (int i = 0; i < 8; i++){
    int c = (lane + i) & 7;
    float y = p.b_gm0[c];
    #pragma unroll
    for (int j = 0; j < 32; j++) y += p.w_gm0[c*32+j]*g[j];
    atomicAdd(&ls[c], y); atomicAdd(&ls[8+c], y*y);
  }
  float w0[8]; wchain0(p, v, w0);
  float w1[8];
  #pragma unroll
  for (int c = 0; c < 8; c++){
    float y = p.b_wn1[c];
    #pragma unroll
    for (int j = 0; j < 8; j++) y += p.w_wn1[c*8+j]*w0[j];
    w1[c] = fmaxf((y - p.fs[G_BN6+c])*p.fs[G_BN6+8+c], 0.f);
  }
  #pragma unroll
  for (int i = 0; i < 16; i++){
    int c = (lane + i) & 15;
    float y = p.b_wn2[c];
    #pragma unroll
    for (int j = 0; j < 8; j++) y += p.w_wn2[c*8+j]*w1[j];
    atomicAdd(&ls[16+c], y); atomicAdd(&ls[32+c], y*y);
  }
  __syncthreads();
  if (t < 8){
    atomicAdd(&p.ds[G_BN3+t], (double)ls[t]);
    atomicAdd(&p.ds[G_BN3+8+t], (double)ls[8+t]);
  } else if (t < 24){
    int c = t - 8;
    atomicAdd(&p.ds[G_BN7+c], (double)ls[16+c]);
    atomicAdd(&p.ds[G_BN7+16+c], (double)ls[32+c]);
  }
}

// ---------------------------------------------------------------- P4: main fused pass → y8/y9 pre-acts + bn8/bn9 moments
__global__ __launch_bounds__(256) void k_main(P p){
  __shared__ float sgf[16*528];        // [pt][k][c] pad33; later aliased as nf[pt][512]
  __shared__ float swv[16][16][20];    // [pt][k][wi] pad20 (float4-aligned)
  __shared__ float smx[16][64];        // per-point max over K of dense_feats
  __shared__ float ls[512];            // bn8 sum/sq [0..255], bn9 sum/sq [256..511]
  int t = threadIdx.x;
  ls[t] = 0.f; ls[t+256] = 0.f;
  __syncthreads();

  int lane = t & 63;
  int k  = lane & 15;
  int pl = (t >> 6)*4 + (lane >> 4);
  int pg = blockIdx.x*16 + pl;
  int b  = pg / Mq;
  int row = pg*16 + k;

  // ---- per-neighbor chain from vi
  float v[12]; load_vi(p, row, v);
  float fp[32]; featpe(p, v, fp);
  float g[32];
  #pragma unroll
  for (int c = 0; c < 32; c++){
    float y = p.b_gu[c];
    #pragma unroll
    for (int j = 0; j < 32; j++) y += p.w_gu[c*32+j]*fp[j];
    g[c] = (y - p.fs[G_BN2+c])*p.fs[G_BN2+32+c];
  }
  #pragma unroll
  for (int c = 0; c < 32; c++){
    float mx = g[c];
    mx = fmaxf(mx, __shfl_xor(mx, 1, 16));
    mx = fmaxf(mx, __shfl_xor(mx, 2, 16));
    mx = fmaxf(mx, __shfl_xor(mx, 4, 16));
    mx = fmaxf(mx, __shfl_xor(mx, 8, 16));
    g[c] -= mx;
  }
  float sc[8];
  #pragma unroll
  for (int c = 0; c < 8; c++){
    float y = p.b_gm0[c];
    #pragma unroll
    for (int j = 0; j < 32; j++) y += p.w_gm0[c*32+j]*g[j];
    sc[c] = fmaxf((y - p.fs[G_BN3+c])*p.fs[G_BN3+8+c], 0.f);
  }
  float scr[4];
  #pragma unroll
  for (int h = 0; h < 4; h++){
    float y = p.b_gm1[h];
    #pragma unroll
    for (int j = 0; j < 8; j++) y += p.w_gm1[h*8+j]*sc[j];
    scr[h] = 1.f/(1.f + expf(-y));
  }
  float w0[8]; wchain0(p, v, w0);
  float w1[8];
  #pragma unroll
  for (int c = 0; c < 8; c++){
    float y = p.b_wn1[c];
    #pragma unroll
    for (int j = 0; j < 8; j++) y += p.w_wn1[c*8+j]*w0[j];
    w1[c] = fmaxf((y - p.fs[G_BN6+c])*p.fs[G_BN6+8+c], 0.f);
  }
  float wv[16];
  #pragma unroll
  for (int c = 0; c < 16; c++){
    float y = p.b_wn2[c];
    #pragma unroll
    for (int j = 0; j < 8; j++) y += p.w_wn2[c*8+j]*w1[j];
    wv[c] = fmaxf((y - p.fs[G_BN7+c])*p.fs[G_BN7+16+c], 0.f);
  }
  {
    float4* d = (float4*)&swv[pl][k][0];
    d[0] = make_float4(wv[0],wv[1],wv[2],wv[3]);
    d[1] = make_float4(wv[4],wv[5],wv[6],wv[7]);
    d[2] = make_float4(wv[8],wv[9],wv[10],wv[11]);
    d[3] = make_float4(wv[12],wv[13],wv[14],wv[15]);
  }

  // ---- dense_feats gather: u1 pre-act + max over K (shfl within 16-lane group)
  int idx = p.nei[row];
  const float4* f4 = (const float4*)(p.dfeat + ((size_t)b*Nq + idx)*64);
  float y4[32];
  #pragma unroll
  for (int c = 0; c < 32; c++) y4[c] = p.b_u1[c];
  #pragma unroll 2
  for (int q = 0; q < 16; q++){
    float4 x = f4[q];
    #pragma unroll
    for (int c = 0; c < 32; c++){
      const float* wr = &p.w_u1[c*64 + q*4];
      y4[c] += wr[0]*x.x + wr[1]*x.y + wr[2]*x.z + wr[3]*x.w;
    }
    float m0=x.x, m1=x.y, m2=x.z, m3=x.w;
    m0=fmaxf(m0,__shfl_xor(m0,1,16)); m0=fmaxf(m0,__shfl_xor(m0,2,16)); m0=fmaxf(m0,__shfl_xor(m0,4,16)); m0=fmaxf(m0,__shfl_xor(m0,8,16));
    m1=fmaxf(m1,__shfl_xor(m1,1,16)); m1=fmaxf(m1,__shfl_xor(m1,2,16)); m1=fmaxf(m1,__shfl_xor(m1,4,16)); m1=fmaxf(m1,__shfl_xor(m1,8,16));
    m2=fmaxf(m2,__shfl_xor(m2,1,16)); m2=fmaxf(m2,__shfl_xor(m2,2,16)); m2=fmaxf(m2,__shfl_xor(m2,4,16)); m2=fmaxf(m2,__shfl_xor(m2,8,16));
    m3=fmaxf(m3,__shfl_xor(m3,1,16)); m3=fmaxf(m3,__shfl_xor(m3,2,16)); m3=fmaxf(m3,__shfl_xor(m3,4,16)); m3=fmaxf(m3,__shfl_xor(m3,8,16));
    if (k == 0) ((float4*)&smx[pl][0])[q] = make_float4(m0,m1,m2,m3);
  }

  // ---- gf = leaky(bn4(y4)) * score[head]
  float* gbase = &sgf[pl*528];
  #pragma unroll
  for (int c = 0; c < 32; c++){
    float fx = lrelu((y4[c] - p.fs[G_BN4+c])*p.fs[G_BN4+32+c]);
    gbase[k*33 + c] = fx*scr[c >> 3];
  }
  __syncthreads();   // gf/wv/smx visible

  // ---- nf[c][wi] = sum_k gf[k][c]*wv[k][wi]; lane handles c0=k, c1=k+16
  float nf0[16], nf1[16];
  #pragma unroll
  for (int wi = 0; wi < 16; wi++){ nf0[wi]=0.f; nf1[wi]=0.f; }
  #pragma unroll 4
  for (int kp = 0; kp < 16; kp++){
    float g0 = gbase[kp*33 + k];
    float g1 = gbase[kp*33 + k + 16];
    const float4* wp4 = (const float4*)&swv[pl][kp][0];
    float4 wa = wp4[0], wb = wp4[1], wc = wp4[2], wd = wp4[3];
    float wvv[16] = {wa.x,wa.y,wa.z,wa.w, wb.x,wb.y,wb.z,wb.w,
                     wc.x,wc.y,wc.z,wc.w, wd.x,wd.y,wd.z,wd.w};
    #pragma unroll
    for (int wi = 0; wi < 16; wi++){ nf0[wi] += g0*wvv[wi]; nf1[wi] += g1*wvv[wi]; }
  }
  __syncthreads();   // all reads of gf done; safe to alias region as nf
  {
    float4* nb = (float4*)gbase;   // nf flat layout [c*16+wi]
    nb[k*4+0]      = make_float4(nf0[0],nf0[1],nf0[2],nf0[3]);
    nb[k*4+1]      = make_float4(nf0[4],nf0[5],nf0[6],nf0[7]);
    nb[k*4+2]      = make_float4(nf0[8],nf0[9],nf0[10],nf0[11]);
    nb[k*4+3]      = make_float4(nf0[12],nf0[13],nf0[14],nf0[15]);
    nb[(k+16)*4+0] = make_float4(nf1[0],nf1[1],nf1[2],nf1[3]);
    nb[(k+16)*4+1] = make_float4(nf1[4],nf1[5],nf1[6],nf1[7]);
    nb[(k+16)*4+2] = make_float4(nf1[8],nf1[9],nf1[10],nf1[11]);
    nb[(k+16)*4+3] = make_float4(nf1[12],nf1[13],nf1[14],nf1[15]);
  }

  // ---- y8 = nf(512) @ u2_w.T : each lane computes 8 of 128 outputs
  float y8a[8];
  #pragma unroll
  for (int j = 0; j < 8; j++) y8a[j] = p.b_u2[k + 16*j];
  const float4* nf4 = (const float4*)gbase;
  #pragma unroll 4
  for (int d4 = 0; d4 < 128; d4++){
    float4 nv = nf4[d4];
    #pragma unroll
    for (int j = 0; j < 8; j++){
      int o = k + 16*j;
      const float4* u4 = (const float4*)(p.w_u2 + (size_t)o*512);
      float4 u = u4[d4];
      y8a[j] += nv.x*u.x + nv.y*u.y + nv.z*u.z + nv.w*u.w;
    }
  }
  #pragma unroll
  for (int j = 0; j < 8; j++){
    int o = k + 16*j;
    float y = y8a[j];
    p.y8[(size_t)pg*128 + o] = y;
    atomicAdd(&ls[o], y); atomicAdd(&ls[128+o], y*y);
  }

  // ---- y9 = max_k(dense_feats) @ us_w.T
  float y9a[8];
  #pragma unroll
  for (int j = 0; j < 8; j++) y9a[j] = p.b_us[k + 16*j];
  const float4* mx4 = (const float4*)&smx[pl][0];
  #pragma unroll
  for (int d4 = 0; d4 < 16; d4++){
    float4 mv = mx4[d4];
    #pragma unroll
    for (int j = 0; j < 8; j++){
      int o = k + 16*j;
      const float4* s4 = (const float4*)(p.w_us + (size_t)o*64);
      float4 u = s4[d4];
      y9a[j] += mv.x*u.x + mv.y*u.y + mv.z*u.z + mv.w*u.w;
    }
  }
  #pragma unroll
  for (int j = 0; j < 8; j++){
    int o = k + 16*j;
    float y = y9a[j];
    p.y9[(size_t)pg*128 + o] = y;
    atomicAdd(&ls[256+o], y); atomicAdd(&ls[384+o], y*y);
  }

  __syncthreads();
  atomicAdd(&p.ds[G_BN8+t], (double)ls[t]);       // bn8 sum+sq
  atomicAdd(&p.ds[G_BN9+t], (double)ls[256+t]);   // bn9 sum+sq
}

// ---------------------------------------------------------------- P5: out = leaky(bn8(y8)+bn9(y9))
__global__ __launch_bounds__(256) void k_out(P p){
  size_t i = ((size_t)blockIdx.x*256 + threadIdx.x)*4;  // 6.4M floats total
  int c = (int)(i & 127);
  float4 a  = *(const float4*)(p.y8 + i);
  float4 b4 = *(const float4*)(p.y9 + i);
  const float* m8 = p.fs + G_BN8;  const float* i8 = p.fs + G_BN8 + 128;
  const float* m9 = p.fs + G_BN9;  const float* i9 = p.fs + G_BN9 + 128;
  float r0 = lrelu((a.x - m8[c  ])*i8[c  ] + (b4.x - m9[c  ])*i9[c  ]);
  float r1 = lrelu((a.y - m8[c+1])*i8[c+1] + (b4.y - m9[c+1])*i9[c+1]);
  float r2 = lrelu((a.z - m8[c+2])*i8[c+2] + (b4.z - m9[c+2])*i9[c+2]);
  float r3 = lrelu((a.w - m8[c+3])*i8[c+3] + (b4.w - m9[c+3])*i9[c+3]);
  *(float4*)(p.out + i) = make_float4(r0,r1,r2,r3);
}

extern "C" void kernel_launch(void* const* d_in, const int* in_sizes, int n_in,
                              void* d_out, int out_size, void* d_ws, size_t ws_size,
                              hipStream_t stream){
  (void)in_sizes; (void)n_in; (void)out_size; (void)ws_size;
  P p;
  p.dxyz  = (const float*)d_in[0];
  p.sxyz  = (const float*)d_in[1];
  p.dfeat = (const float*)d_in[2];
  p.dnorm = (const float*)d_in[3];
  p.snorm = (const float*)d_in[4];
  p.w_mlp = (const float*)d_in[5];  p.b_mlp = (const float*)d_in[6];
  p.w_gu  = (const float*)d_in[7];  p.b_gu  = (const float*)d_in[8];
  p.w_gm0 = (const float*)d_in[9];  p.b_gm0 = (const float*)d_in[10];
  p.w_gm1 = (const float*)d_in[11]; p.b_gm1 = (const float*)d_in[12];
  p.w_u1  = (const float*)d_in[13]; p.b_u1  = (const float*)d_in[14];
  p.w_wn0 = (const float*)d_in[15]; p.b_wn0 = (const float*)d_in[16];
  p.w_wn1 = (const float*)d_in[17]; p.b_wn1 = (const float*)d_in[18];
  p.w_wn2 = (const float*)d_in[19]; p.b_wn2 = (const float*)d_in[20];
  p.w_u2  = (const float*)d_in[21]; p.b_u2  = (const float*)d_in[22];
  p.w_us  = (const float*)d_in[23]; p.b_us  = (const float*)d_in[24];
  p.nei   = (const int*)d_in[25];
  char* ws = (char*)d_ws;
  p.vi = (float*)(ws + OFF_VI);
  p.y8 = (float*)(ws + OFF_Y8);
  p.y9 = (float*)(ws + OFF_Y9);
  p.ds = (double*)(ws + OFF_DS);
  p.fs = (float*)(ws + OFF_FS);
  p.out = (float*)d_out;

  hipMemsetAsync(ws + OFF_DS, 0, 784*sizeof(double), stream);

  k_vi  <<<3125, 256, 0, stream>>>(p);   // 800000 rows
  k_u1s <<< 782, 256, 0, stream>>>(p);   // 200000 rows (guarded)
  k_fin1<<<   1, 128, 0, stream>>>(p);
  k_s2  <<<3125, 256, 0, stream>>>(p);
  k_fin2<<<   1, 128, 0, stream>>>(p);
  k_s3  <<<3125, 256, 0, stream>>>(p);
  k_fin3<<<   1, 128, 0, stream>>>(p);
  k_main<<<3125, 256, 0, stream>>>(p);
  k_fin4<<<   1, 128, 0, stream>>>(p);
  k_out <<<6250, 256, 0, stream>>>(p);   // 6.4M floats / 4
}

// Round 2
// 1521.866 us; speedup vs baseline: 2.0843x; 2.0843x over previous
//
#include <hip/hip_runtime.h>
#include <math.h>

// Problem constants (B,N,M,K from reference setup_inputs)
constexpr int Bq = 2;
constexpr int Nq = 100000;
constexpr int Mq = 25000;
constexpr int Kq = 16;
// rows of (B,M,K) = 800000 = 625*1280 ; B*M = 50000 pts = 625*80

// ---- workspace layout (bytes) ----
constexpr size_t OFF_VI  = 0;              // 800000*12*4  = 38,400,000
constexpr size_t OFF_Y8  = 38400000;       // 50000*128*4  = 25,600,000
constexpr size_t OFF_Y9  = 64000000;       // 25,600,000
constexpr size_t OFF_DS  = 89600000;       // 784 doubles
constexpr size_t OFF_FS  = OFF_DS + 8192;  // 784 floats
constexpr size_t OFF_WT2 = OFF_DS + 16384; // 512*128*4 = 262144 (u2 transposed)
constexpr size_t OFF_WTS = OFF_WT2 + 262144; // 64*128*4 = 32768 (us transposed)
// total ~89.9 MB

// ---- stat-group offsets: [off..off+C) sum→mean, [off+C..off+2C) sumsq→invstd
constexpr int G_BN1 = 0;    // C=32  n=800000  mlp_conv pre-act
constexpr int G_BN5 = 64;   // C=8   n=800000  wn0 pre-act
constexpr int G_BN4 = 80;   // C=32  n=200000  u1 pre-act
constexpr int G_BN2 = 144;  // C=32  n=800000  gu pre-act
constexpr int G_BN6 = 208;  // C=8   n=800000  wn1 pre-act
constexpr int G_BN3 = 224;  // C=8   n=800000  gm0 pre-act
constexpr int G_BN7 = 240;  // C=16  n=800000  wn2 pre-act
constexpr int G_BN8 = 272;  // C=128 n=50000   u2 pre-act
constexpr int G_BN9 = 528;  // C=128 n=50000   us pre-act

struct P {
  const float *dxyz,*sxyz,*dfeat,*dnorm,*snorm;
  const float *w_mlp,*b_mlp,*w_gu,*b_gu,*w_gm0,*b_gm0,*w_gm1,*b_gm1;
  const float *w_u1,*b_u1,*w_wn0,*b_wn0,*w_wn1,*b_wn1,*w_wn2,*b_wn2;
  const float *w_u2,*b_u2,*w_us,*b_us;
  const int* nei;
  float* vi; float* y8; float* y9; double* ds; float* fs;
  float* wt2; float* ust; float* out;
};

__device__ __forceinline__ float lrelu(float x){ return x > 0.f ? x : 0.1f*x; }

// ---------------------------------------------------------------- k_tr: transpose u2/us weights to [d][o]
__global__ __launch_bounds__(256) void k_tr(P p){
  int i = blockIdx.x*256 + threadIdx.x;       // 65536 threads
  int d = i >> 7, o = i & 127;
  p.wt2[i] = p.w_u2[(size_t)o*512 + d];
  if (i < 64*128) p.ust[i] = p.w_us[(size_t)o*64 + d];
}

// ---------------------------------------------------------------- P1: vi + bn1/bn5 moments (5 rows/thread)
__global__ __launch_bounds__(256) void k_vi(P p){
  __shared__ float ls[80];
  int t = threadIdx.x;
  if (t < 80) ls[t] = 0.f;
  __syncthreads();

  float a1[32], q1[32], a5[8], q5[8];
  #pragma unroll
  for (int c = 0; c < 32; c++){ a1[c]=0.f; q1[c]=0.f; }
  #pragma unroll
  for (int c = 0; c < 8; c++){ a5[c]=0.f; q5[c]=0.f; }

  int base = blockIdx.x*1280 + t;             // 625 blocks cover 800000 rows
  for (int r = 0; r < 5; r++){
    int row = base + r*256;
    int b   = row / (Mq*Kq);
    int rem = row - b*(Mq*Kq);
    int m   = rem >> 4;
    int bm  = b*Mq + m;
    int idx = p.nei[row];

    const float* gx = p.dxyz  + ((size_t)b*Nq + idx)*3;
    const float* gn = p.dnorm + ((size_t)b*Nq + idx)*3;
    const float* sx = p.sxyz  + (size_t)bm*3;
    const float* sn = p.snorm + (size_t)bm*3;

    float lx = gx[0]-sx[0], ly = gx[1]-sx[1], lz = gx[2]-sx[2];
    float gnx = gn[0], gny = gn[1], gnz = gn[2];
    float snx = sn[0], sny = sn[1], snz = sn[2];

    float rn = sqrtf(lx*lx + ly*ly + lz*lz);
    float rd = fmaxf(rn, 1e-12f);
    float rx = lx/rd, ry = ly/rd, rz = lz/rd;
    float proj = snx*rx + sny*ry + snz*rz;
    float vx = snx - proj*rx, vy = sny - proj*ry, vz = snz - proj*rz;
    float vn = sqrtf(vx*vx + vy*vy + vz*vz);
    float vd = fmaxf(vn, 1e-12f);
    vx /= vd; vy /= vd; vz /= vd;
    float wx = ry*vz - rz*vy, wy = rz*vx - rx*vz, wz = rx*vy - ry*vx;
    float wnn = sqrtf(wx*wx + wy*wy + wz*wz);
    float wd = fmaxf(wnn, 1e-12f);
    wx /= wd; wy /= wd; wz /= wd;
    float cx = gny*snz - gnz*sny, cy = gnz*snx - gnx*snz, cz = gnx*sny - gny*snx;

    float v[12];
    v[0] = gnx*snx + gny*sny + gnz*snz;
    v[1] = proj;
    v[2] = rx*gnx + ry*gny + rz*gnz;
    v[3] = lx*snx + ly*sny + lz*snz;
    v[4] = v[2];
    v[5] = gnx*vx + gny*vy + gnz*vz;
    v[6] = gnx*wx + gny*wy + gnz*wz;
    v[7] = lx*cx + ly*cy + lz*cz;
    v[8] = rn;
    v[9] = lx; v[10] = ly; v[11] = lz;

    float4* vo = (float4*)(p.vi + (size_t)row*12);
    vo[0] = make_float4(v[0],v[1],v[2],v[3]);
    vo[1] = make_float4(v[4],v[5],v[6],v[7]);
    vo[2] = make_float4(v[8],v[9],v[10],v[11]);

    #pragma unroll
    for (int c = 0; c < 32; c++){
      float y = p.b_mlp[c];
      #pragma unroll
      for (int j = 0; j < 12; j++) y += p.w_mlp[c*12 + j]*v[j];
      a1[c] += y; q1[c] += y*y;
    }
    #pragma unroll
    for (int c = 0; c < 8; c++){
      float y = p.b_wn0[c];
      #pragma unroll
      for (int j = 0; j < 12; j++) y += p.w_wn0[c*12 + j]*v[j];
      a5[c] += y; q5[c] += y*y;
    }
  }
  int lane = t & 63;
  #pragma unroll
  for (int i = 0; i < 32; i++){
    int c = (lane + i) & 31;
    atomicAdd(&ls[c], a1[c]); atomicAdd(&ls[32+c], q1[c]);
  }
  #pragma unroll
  for (int i = 0; i < 8; i++){
    int c = (lane + i) & 7;
    atomicAdd(&ls[64+c], a5[c]); atomicAdd(&ls[72+c], q5[c]);
  }
  __syncthreads();
  if (t < 32){
    atomicAdd(&p.ds[G_BN1+t], (double)ls[t]);
    atomicAdd(&p.ds[G_BN1+32+t], (double)ls[32+t]);
  } else if (t < 40){
    int c = t - 32;
    atomicAdd(&p.ds[G_BN5+c], (double)ls[64+c]);
    atomicAdd(&p.ds[G_BN5+8+c], (double)ls[72+c]);
  }
}

// ---------------------------------------------------------------- P1b: bn4 (u1) moments over B*N (5 rows/thread)
__global__ __launch_bounds__(256) void k_u1s(P p){
  __shared__ float ls[64];
  int t = threadIdx.x;
  if (t < 64) ls[t] = 0.f;
  __syncthreads();
  float a4[32], q4[32];
  #pragma unroll
  for (int c = 0; c < 32; c++){ a4[c]=0.f; q4[c]=0.f; }
  int base = blockIdx.x*1280 + t;             // 157 blocks, guard to 200000
  for (int r = 0; r < 5; r++){
    int row = base + r*256;
    if (row < Bq*Nq){
      const float4* f4 = (const float4*)(p.dfeat + (size_t)row*64);
      float fr[64];
      #pragma unroll
      for (int q = 0; q < 16; q++){
        float4 x = f4[q];
        fr[q*4+0]=x.x; fr[q*4+1]=x.y; fr[q*4+2]=x.z; fr[q*4+3]=x.w;
      }
      #pragma unroll
      for (int c = 0; c < 32; c++){
        float y = p.b_u1[c];
        #pragma unroll
        for (int j = 0; j < 64; j++) y += p.w_u1[c*64 + j]*fr[j];
        a4[c] += y; q4[c] += y*y;
      }
    }
  }
  int lane = t & 63;
  #pragma unroll
  for (int i = 0; i < 32; i++){
    int c = (lane + i) & 31;
    atomicAdd(&ls[c], a4[c]); atomicAdd(&ls[32+c], q4[c]);
  }
  __syncthreads();
  if (t < 32){
    atomicAdd(&p.ds[G_BN4+t], (double)ls[t]);
    atomicAdd(&p.ds[G_BN4+32+t], (double)ls[32+t]);
  }
}

// ---------------------------------------------------------------- stat finalize
__device__ __forceinline__ void fin_group(const double* ds, float* fs, int off, int C, double n){
  for (int c = threadIdx.x; c < C; c += blockDim.x){
    double s = ds[off+c], q = ds[off+C+c];
    double mu = s/n;
    double va = q/n - mu*mu;
    if (va < 0.0) va = 0.0;
    fs[off+c]   = (float)mu;
    fs[off+C+c] = 1.f/sqrtf((float)va + 1e-5f);
  }
}
__global__ void k_fin1(P p){ fin_group(p.ds,p.fs,G_BN1,32,800000.0); fin_group(p.ds,p.fs,G_BN5,8,800000.0); fin_group(p.ds,p.fs,G_BN4,32,200000.0); }
__global__ void k_fin2(P p){ fin_group(p.ds,p.fs,G_BN2,32,800000.0); fin_group(p.ds,p.fs,G_BN6,8,800000.0); }
__global__ void k_fin3(P p){ fin_group(p.ds,p.fs,G_BN3,8,800000.0);  fin_group(p.ds,p.fs,G_BN7,16,800000.0); }
__global__ void k_fin4(P p){ fin_group(p.ds,p.fs,G_BN8,128,50000.0); fin_group(p.ds,p.fs,G_BN9,128,50000.0); }

// helpers to recompute the small chains from vi
__device__ __forceinline__ void load_vi(const P& p, int row, float v[12]){
  const float4* vp = (const float4*)(p.vi + (size_t)row*12);
  float4 a = vp[0], b = vp[1], c = vp[2];
  v[0]=a.x; v[1]=a.y; v[2]=a.z; v[3]=a.w;
  v[4]=b.x; v[5]=b.y; v[6]=b.z; v[7]=b.w;
  v[8]=c.x; v[9]=c.y; v[10]=c.z; v[11]=c.w;
}
__device__ __forceinline__ void featpe(const P& p, const float v[12], float fp[32]){
  #pragma unroll
  for (int c = 0; c < 32; c++){
    float y = p.b_mlp[c];
    #pragma unroll
    for (int j = 0; j < 12; j++) y += p.w_mlp[c*12+j]*v[j];
    fp[c] = fmaxf((y - p.fs[G_BN1+c])*p.fs[G_BN1+32+c], 0.f);
  }
}
__device__ __forceinline__ void wchain0(const P& p, const float v[12], float w0[8]){
  #pragma unroll
  for (int c = 0; c < 8; c++){
    float y = p.b_wn0[c];
    #pragma unroll
    for (int j = 0; j < 12; j++) y += p.w_wn0[c*12+j]*v[j];
    w0[c] = fmaxf((y - p.fs[G_BN5+c])*p.fs[G_BN5+8+c], 0.f);
  }
}

// ---------------------------------------------------------------- P2: bn2/bn6 moments (5 rows/thread)
__global__ __launch_bounds__(256) void k_s2(P p){
  __shared__ float ls[80];
  int t = threadIdx.x;
  if (t < 80) ls[t] = 0.f;
  __syncthreads();
  float a2[32], q2[32], a6[8], q6[8];
  #pragma unroll
  for (int c = 0; c < 32; c++){ a2[c]=0.f; q2[c]=0.f; }
  #pragma unroll
  for (int c = 0; c < 8; c++){ a6[c]=0.f; q6[c]=0.f; }
  int base = blockIdx.x*1280 + t;
  for (int r = 0; r < 5; r++){
    int row = base + r*256;
    float v[12]; load_vi(p, row, v);
    float fp[32]; featpe(p, v, fp);
    #pragma unroll
    for (int c = 0; c < 32; c++){
      float y = p.b_gu[c];
      #pragma unroll
      for (int j = 0; j < 32; j++) y += p.w_gu[c*32+j]*fp[j];
      a2[c] += y; q2[c] += y*y;
    }
    float w0[8]; wchain0(p, v, w0);
    #pragma unroll
    for (int c = 0; c < 8; c++){
      float y = p.b_wn1[c];
      #pragma unroll
      for (int j = 0; j < 8; j++) y += p.w_wn1[c*8+j]*w0[j];
      a6[c] += y; q6[c] += y*y;
    }
  }
  int lane = t & 63;
  #pragma unroll
  for (int i = 0; i < 32; i++){
    int c = (lane + i) & 31;
    atomicAdd(&ls[c], a2[c]); atomicAdd(&ls[32+c], q2[c]);
  }
  #pragma unroll
  for (int i = 0; i < 8; i++){
    int c = (lane + i) & 7;
    atomicAdd(&ls[64+c], a6[c]); atomicAdd(&ls[72+c], q6[c]);
  }
  __syncthreads();
  if (t < 32){
    atomicAdd(&p.ds[G_BN2+t], (double)ls[t]);
    atomicAdd(&p.ds[G_BN2+32+t], (double)ls[32+t]);
  } else if (t < 40){
    int c = t - 32;
    atomicAdd(&p.ds[G_BN6+c], (double)ls[64+c]);
    atomicAdd(&p.ds[G_BN6+8+c], (double)ls[72+c]);
  }
}

// ---------------------------------------------------------------- P3: bn3/bn7 moments (5 point-groups/block)
__global__ __launch_bounds__(256) void k_s3(P p){
  __shared__ float ls[48];
  int t = threadIdx.x;
  if (t < 48) ls[t] = 0.f;
  __syncthreads();
  int lane = t & 63;
  int k  = lane & 15;
  int pl = (t >> 6)*4 + (lane >> 4);
  float a3[8], q3[8], a7[16], q7[16];
  #pragma unroll
  for (int c = 0; c < 8; c++){ a3[c]=0.f; q3[c]=0.f; }
  #pragma unroll
  for (int c = 0; c < 16; c++){ a7[c]=0.f; q7[c]=0.f; }

  for (int it = 0; it < 5; it++){
    int pg = blockIdx.x*80 + it*16 + pl;      // 625 blocks cover 50000 pts
    int row = pg*16 + k;
    float v[12]; load_vi(p, row, v);
    float fp[32]; featpe(p, v, fp);
    float g[32];
    #pragma unroll
    for (int c = 0; c < 32; c++){
      float y = p.b_gu[c];
      #pragma unroll
      for (int j = 0; j < 32; j++) y += p.w_gu[c*32+j]*fp[j];
      g[c] = (y - p.fs[G_BN2+c])*p.fs[G_BN2+32+c];
    }
    #pragma unroll
    for (int c = 0; c < 32; c++){
      float mx = g[c];
      mx = fmaxf(mx, __shfl_xor(mx, 1, 16));
      mx = fmaxf(mx, __shfl_xor(mx, 2, 16));
      mx = fmaxf(mx, __shfl_xor(mx, 4, 16));
      mx = fmaxf(mx, __shfl_xor(mx, 8, 16));
      g[c] -= mx;
    }
    #pragma unroll
    for (int c = 0; c < 8; c++){
      float y = p.b_gm0[c];
      #pragma unroll
      for (int j = 0; j < 32; j++) y += p.w_gm0[c*32+j]*g[j];
      a3[c] += y; q3[c] += y*y;
    }
    float w0[8]; wchain0(p, v, w0);
    float w1[8];
    #pragma unroll
    for (int c = 0; c < 8; c++){
      float y = p.b_wn1[c];
      #pragma unroll
      for (int j = 0; j < 8; j++) y += p.w_wn1[c*8+j]*w0[j];
      w1[c] = fmaxf((y - p.fs[G_BN6+c])*p.fs[G_BN6+8+c], 0.f);
    }
    #pragma unroll
    for (int c = 0; c < 16; c++){
      float y = p.b_wn2[c];
      #pragma unroll
      for (int j = 0; j < 8; j++) y += p.w_wn2[c*8+j]*w1[j];
      a7[c] += y; q7[c] += y*y;
    }
  }
  #pragma unroll
  for (int i = 0; i < 8; i++){
    int c = (lane + i) & 7;
    atomicAdd(&ls[c], a3[c]); atomicAdd(&ls[8+c], q3[c]);
  }
  #pragma unroll
  for (int i = 0; i < 16; i++){
    int c = (lane + i) & 15;
    atomicAdd(&ls[16+c], a7[c]); atomicAdd(&ls[32+c], q7[c]);
  }
  __syncthreads();
  if (t < 8){
    atomicAdd(&p.ds[G_BN3+t], (double)ls[t]);
    atomicAdd(&p.ds[G_BN3+8+t], (double)ls[8+t]);
  } else if (t < 24){
    int c = t - 8;
    atomicAdd(&p.ds[G_BN7+c], (double)ls[16+c]);
    atomicAdd(&p.ds[G_BN7+16+c], (double)ls[32+c]);
  }
}

// ---------------------------------------------------------------- P4: main fused pass → y8/y9 pre-acts + bn8/bn9 moments
__global__ __launch_bounds__(256) void k_main(P p){
  __shared__ float sgf[16*528];        // [pt][k*33+c]; after barrier aliased as nf[pt*528 + d]
  __shared__ float swv[16][16][20];    // [pt][k][wi]
  __shared__ float smx[16][64];        // per-point max over K of dense_feats
  __shared__ float ls[512];            // bn8 sum/sq [0..255], bn9 sum/sq [256..511]
  int t = threadIdx.x;
  ls[t] = 0.f; ls[t+256] = 0.f;
  __syncthreads();

  int lane = t & 63;
  int k  = lane & 15;
  int pl = (t >> 6)*4 + (lane >> 4);
  int pg = blockIdx.x*16 + pl;
  int b  = pg / Mq;
  int row = pg*16 + k;

  // ---- per-neighbor chain from vi
  float v[12]; load_vi(p, row, v);
  float fp[32]; featpe(p, v, fp);
  float g[32];
  #pragma unroll
  for (int c = 0; c < 32; c++){
    float y = p.b_gu[c];
    #pragma unroll
    for (int j = 0; j < 32; j++) y += p.w_gu[c*32+j]*fp[j];
    g[c] = (y - p.fs[G_BN2+c])*p.fs[G_BN2+32+c];
  }
  #pragma unroll
  for (int c = 0; c < 32; c++){
    float mx = g[c];
    mx = fmaxf(mx, __shfl_xor(mx, 1, 16));
    mx = fmaxf(mx, __shfl_xor(mx, 2, 16));
    mx = fmaxf(mx, __shfl_xor(mx, 4, 16));
    mx = fmaxf(mx, __shfl_xor(mx, 8, 16));
    g[c] -= mx;
  }
  float sc[8];
  #pragma unroll
  for (int c = 0; c < 8; c++){
    float y = p.b_gm0[c];
    #pragma unroll
    for (int j = 0; j < 32; j++) y += p.w_gm0[c*32+j]*g[j];
    sc[c] = fmaxf((y - p.fs[G_BN3+c])*p.fs[G_BN3+8+c], 0.f);
  }
  float scr[4];
  #pragma unroll
  for (int h = 0; h < 4; h++){
    float y = p.b_gm1[h];
    #pragma unroll
    for (int j = 0; j < 8; j++) y += p.w_gm1[h*8+j]*sc[j];
    scr[h] = 1.f/(1.f + expf(-y));
  }
  float w0[8]; wchain0(p, v, w0);
  float w1[8];
  #pragma unroll
  for (int c = 0; c < 8; c++){
    float y = p.b_wn1[c];
    #pragma unroll
    for (int j = 0; j < 8; j++) y += p.w_wn1[c*8+j]*w0[j];
    w1[c] = fmaxf((y - p.fs[G_BN6+c])*p.fs[G_BN6+8+c], 0.f);
  }
  float wv[16];
  #pragma unroll
  for (int c = 0; c < 16; c++){
    float y = p.b_wn2[c];
    #pragma unroll
    for (int j = 0; j < 8; j++) y += p.w_wn2[c*8+j]*w1[j];
    wv[c] = fmaxf((y - p.fs[G_BN7+c])*p.fs[G_BN7+16+c], 0.f);
  }
  {
    float4* d = (float4*)&swv[pl][k][0];
    d[0] = make_float4(wv[0],wv[1],wv[2],wv[3]);
    d[1] = make_float4(wv[4],wv[5],wv[6],wv[7]);
    d[2] = make_float4(wv[8],wv[9],wv[10],wv[11]);
    d[3] = make_float4(wv[12],wv[13],wv[14],wv[15]);
  }

  // ---- dense_feats gather into registers (all 16 loads in flight)
  int idx = p.nei[row];
  const float4* f4 = (const float4*)(p.dfeat + ((size_t)b*Nq + idx)*64);
  float fr[64];
  #pragma unroll
  for (int q = 0; q < 16; q++){
    float4 x = f4[q];
    fr[q*4+0]=x.x; fr[q*4+1]=x.y; fr[q*4+2]=x.z; fr[q*4+3]=x.w;
  }
  // u1 pre-act → bn4 → leaky → *score → gf in LDS
  float* gbase = &sgf[pl*528];
  #pragma unroll
  for (int c = 0; c < 32; c++){
    float y = p.b_u1[c];
    #pragma unroll
    for (int j = 0; j < 64; j++) y += p.w_u1[c*64 + j]*fr[j];
    float fx = lrelu((y - p.fs[G_BN4+c])*p.fs[G_BN4+32+c]);
    gbase[k*33 + c] = fx*scr[c >> 3];
  }
  // max over K of dense_feats (shfl within 16-lane group)
  #pragma unroll
  for (int q = 0; q < 16; q++){
    float m0=fr[q*4+0], m1=fr[q*4+1], m2=fr[q*4+2], m3=fr[q*4+3];
    m0=fmaxf(m0,__shfl_xor(m0,1,16)); m0=fmaxf(m0,__shfl_xor(m0,2,16)); m0=fmaxf(m0,__shfl_xor(m0,4,16)); m0=fmaxf(m0,__shfl_xor(m0,8,16));
    m1=fmaxf(m1,__shfl_xor(m1,1,16)); m1=fmaxf(m1,__shfl_xor(m1,2,16)); m1=fmaxf(m1,__shfl_xor(m1,4,16)); m1=fmaxf(m1,__shfl_xor(m1,8,16));
    m2=fmaxf(m2,__shfl_xor(m2,1,16)); m2=fmaxf(m2,__shfl_xor(m2,2,16)); m2=fmaxf(m2,__shfl_xor(m2,4,16)); m2=fmaxf(m2,__shfl_xor(m2,8,16));
    m3=fmaxf(m3,__shfl_xor(m3,1,16)); m3=fmaxf(m3,__shfl_xor(m3,2,16)); m3=fmaxf(m3,__shfl_xor(m3,4,16)); m3=fmaxf(m3,__shfl_xor(m3,8,16));
    if (k == 0) ((float4*)&smx[pl][0])[q] = make_float4(m0,m1,m2,m3);
  }
  __syncthreads();   // gf/swv/smx visible

  // ---- nf[c][wi] = sum_k gf[k][c]*wv[k][wi]; lane handles c0=k, c1=k+16
  float nf0[16], nf1[16];
  #pragma unroll
  for (int wi = 0; wi < 16; wi++){ nf0[wi]=0.f; nf1[wi]=0.f; }
  #pragma unroll 4
  for (int kp = 0; kp < 16; kp++){
    float g0 = gbase[kp*33 + k];
    float g1 = gbase[kp*33 + k + 16];
    const float4* wp4 = (const float4*)&swv[pl][kp][0];
    float4 wa = wp4[0], wb = wp4[1], wc = wp4[2], wd = wp4[3];
    float wvv[16] = {wa.x,wa.y,wa.z,wa.w, wb.x,wb.y,wb.z,wb.w,
                     wc.x,wc.y,wc.z,wc.w, wd.x,wd.y,wd.z,wd.w};
    #pragma unroll
    for (int wi = 0; wi < 16; wi++){ nf0[wi] += g0*wvv[wi]; nf1[wi] += g1*wvv[wi]; }
  }
  __syncthreads();   // all reads of gf done; alias region as nf[pt*528 + d], d=c*16+wi
  {
    float4* nb = (float4*)gbase;
    nb[k*4+0]      = make_float4(nf0[0],nf0[1],nf0[2],nf0[3]);
    nb[k*4+1]      = make_float4(nf0[4],nf0[5],nf0[6],nf0[7]);
    nb[k*4+2]      = make_float4(nf0[8],nf0[9],nf0[10],nf0[11]);
    nb[k*4+3]      = make_float4(nf0[12],nf0[13],nf0[14],nf0[15]);
    nb[(k+16)*4+0] = make_float4(nf1[0],nf1[1],nf1[2],nf1[3]);
    nb[(k+16)*4+1] = make_float4(nf1[4],nf1[5],nf1[6],nf1[7]);
    nb[(k+16)*4+2] = make_float4(nf1[8],nf1[9],nf1[10],nf1[11]);
    nb[(k+16)*4+3] = make_float4(nf1[12],nf1[13],nf1[14],nf1[15]);
  }
  __syncthreads();   // nf visible block-wide

  // ---- y8: thread owns channel o, half-block owns 8 points. Coalesced wt2 reads.
  int o   = t & 127;
  int ptb = (t >> 7)*8;
  float acc[8];
  #pragma unroll
  for (int i = 0; i < 8; i++) acc[i] = p.b_u2[o];
  #pragma unroll 2
  for (int d4 = 0; d4 < 128; d4++){
    float wa = p.wt2[(4*d4+0)*128 + o];
    float wb = p.wt2[(4*d4+1)*128 + o];
    float wc = p.wt2[(4*d4+2)*128 + o];
    float wd = p.wt2[(4*d4+3)*128 + o];
    #pragma unroll
    for (int i = 0; i < 8; i++){
      float4 nv = *(const float4*)(&sgf[(ptb+i)*528 + 4*d4]);
      acc[i] += nv.x*wa + nv.y*wb + nv.z*wc + nv.w*wd;
    }
  }
  size_t obase = (size_t)(blockIdx.x*16)*128 + o;
  {
    float s8=0.f, q8=0.f;
    #pragma unroll
    for (int i = 0; i < 8; i++){
      float y = acc[i];
      p.y8[obase + (size_t)(ptb+i)*128] = y;
      s8 += y; q8 += y*y;
    }
    atomicAdd(&ls[o], s8); atomicAdd(&ls[128+o], q8);
  }

  // ---- y9: same structure from smx via transposed us
  float ac9[8];
  #pragma unroll
  for (int i = 0; i < 8; i++) ac9[i] = p.b_us[o];
  #pragma unroll 4
  for (int d4 = 0; d4 < 16; d4++){
    float wa = p.ust[(4*d4+0)*128 + o];
    float wb = p.ust[(4*d4+1)*128 + o];
    float wc = p.ust[(4*d4+2)*128 + o];
    float wd = p.ust[(4*d4+3)*128 + o];
    #pragma unroll
    for (int i = 0; i < 8; i++){
      float4 nv = *(const float4*)(&smx[ptb+i][4*d4]);
      ac9[i] += nv.x*wa + nv.y*wb + nv.z*wc + nv.w*wd;
    }
  }
  {
    float s9=0.f, q9=0.f;
    #pragma unroll
    for (int i = 0; i < 8; i++){
      float y = ac9[i];
      p.y9[obase + (size_t)(ptb+i)*128] = y;
      s9 += y; q9 += y*y;
    }
    atomicAdd(&ls[256+o], s9); atomicAdd(&ls[384+o], q9);
  }

  __syncthreads();
  atomicAdd(&p.ds[G_BN8+t], (double)ls[t]);
  atomicAdd(&p.ds[G_BN9+t], (double)ls[256+t]);
}

// ---------------------------------------------------------------- P5: out = leaky(bn8(y8)+bn9(y9))
__global__ __launch_bounds__(256) void k_out(P p){
  size_t i = ((size_t)blockIdx.x*256 + threadIdx.x)*4;
  int c = (int)(i & 127);
  float4 a  = *(const float4*)(p.y8 + i);
  float4 b4 = *(const float4*)(p.y9 + i);
  const float* m8 = p.fs + G_BN8;  const float* i8 = p.fs + G_BN8 + 128;
  const float* m9 = p.fs + G_BN9;  const float* i9 = p.fs + G_BN9 + 128;
  float r0 = lrelu((a.x - m8[c  ])*i8[c  ] + (b4.x - m9[c  ])*i9[c  ]);
  float r1 = lrelu((a.y - m8[c+1])*i8[c+1] + (b4.y - m9[c+1])*i9[c+1]);
  float r2 = lrelu((a.z - m8[c+2])*i8[c+2] + (b4.z - m9[c+2])*i9[c+2]);
  float r3 = lrelu((a.w - m8[c+3])*i8[c+3] + (b4.w - m9[c+3])*i9[c+3]);
  *(float4*)(p.out + i) = make_float4(r0,r1,r2,r3);
}

extern "C" void kernel_launch(void* const* d_in, const int* in_sizes, int n_in,
                              void* d_out, int out_size, void* d_ws, size_t ws_size,
                              hipStream_t stream){
  (void)in_sizes; (void)n_in; (void)out_size; (void)ws_size;
  P p;
  p.dxyz  = (const float*)d_in[0];
  p.sxyz  = (const float*)d_in[1];
  p.dfeat = (const float*)d_in[2];
  p.dnorm = (const float*)d_in[3];
  p.snorm = (const float*)d_in[4];
  p.w_mlp = (const float*)d_in[5];  p.b_mlp = (const float*)d_in[6];
  p.w_gu  = (const float*)d_in[7];  p.b_gu  = (const float*)d_in[8];
  p.w_gm0 = (const float*)d_in[9];  p.b_gm0 = (const float*)d_in[10];
  p.w_gm1 = (const float*)d_in[11]; p.b_gm1 = (const float*)d_in[12];
  p.w_u1  = (const float*)d_in[13]; p.b_u1  = (const float*)d_in[14];
  p.w_wn0 = (const float*)d_in[15]; p.b_wn0 = (const float*)d_in[16];
  p.w_wn1 = (const float*)d_in[17]; p.b_wn1 = (const float*)d_in[18];
  p.w_wn2 = (const float*)d_in[19]; p.b_wn2 = (const float*)d_in[20];
  p.w_u2  = (const float*)d_in[21]; p.b_u2  = (const float*)d_in[22];
  p.w_us  = (const float*)d_in[23]; p.b_us  = (const float*)d_in[24];
  p.nei   = (const int*)d_in[25];
  char* ws = (char*)d_ws;
  p.vi  = (float*)(ws + OFF_VI);
  p.y8  = (float*)(ws + OFF_Y8);
  p.y9  = (float*)(ws + OFF_Y9);
  p.ds  = (double*)(ws + OFF_DS);
  p.fs  = (float*)(ws + OFF_FS);
  p.wt2 = (float*)(ws + OFF_WT2);
  p.ust = (float*)(ws + OFF_WTS);
  p.out = (float*)d_out;

  hipMemsetAsync(ws + OFF_DS, 0, 784*sizeof(double), stream);

  k_tr  <<< 256, 256, 0, stream>>>(p);
  k_vi  <<< 625, 256, 0, stream>>>(p);   // 800000 rows, 5/thread
  k_u1s <<< 157, 256, 0, stream>>>(p);   // 200000 rows, 5/thread (guarded)
  k_fin1<<<   1, 128, 0, stream>>>(p);
  k_s2  <<< 625, 256, 0, stream>>>(p);
  k_fin2<<<   1, 128, 0, stream>>>(p);
  k_s3  <<< 625, 256, 0, stream>>>(p);
  k_fin3<<<   1, 128, 0, stream>>>(p);
  k_main<<<3125, 256, 0, stream>>>(p);
  k_fin4<<<   1, 128, 0, stream>>>(p);
  k_out <<<6250, 256, 0, stream>>>(p);   // 6.4M floats / 4
}